// Round 9
// baseline (724.767 us; speedup 1.0000x reference)
//
#include <hip/hip_runtime.h>

#define T_STEPS 100
#define B_SZ    2048
#define IN_DIM  784
#define HID_DIM 100
#define OUT_DIM 10
#define BN      112           // padded hidden (7 x 16)
#define BMR     64            // rows per block (wave = 16 rows x 112 cols)
#define KC      16
#define NSTEP   (IN_DIM / KC) // 49
#define XLP     84            // x LDS k-stride: stores 2-way (4*84%32==16), reads <=3-way
#define WLP     112           // w LDS k-stride: 112%32==16 -> free frag reads, 2-way stores

typedef double f64x4 __attribute__((ext_vector_type(4)));
#define MFMA64(a, b, c) __builtin_amdgcn_mfma_f64_16x16x4f64((a), (b), (c), 0, 0, 0)

// ---------------- pad w1 to [112][784] float (rows 100..111 = 0) ----------------
__global__ void pad_w1(const float* __restrict__ w1, float* __restrict__ w1p) {
  int i = blockIdx.x * 256 + threadIdx.x;
  if (i < BN * IN_DIM) w1p[i] = (i < HID_DIM * IN_DIM) ? w1[i] : 0.0f;
}

// ---------------- Phase A: fp64 MFMA GEMM, self-calibrated D-map, 4 waves/SIMD ----------------
__global__ __launch_bounds__(256, 4)
void snn_gemm1(const float* __restrict__ x,     // [rows][784] (chunk-offset)
               const float* __restrict__ w1p,   // [112][784]
               double* __restrict__ cur)        // [rows][112]
{
  const int tid  = threadIdx.x;
  const int lane = tid & 63;
  const int wv   = tid >> 6;      // 0..3
  const int kg   = lane >> 4;     // 0..3 (k-slot label)
  const int il   = lane & 15;     // row/col label
  const long rowBase = (long)blockIdx.x * BMR;

  __shared__ float xls[2][KC][XLP];   // 10752 B
  __shared__ float wls[2][KC][WLP];   // 14336 B

  // staging maps
  // x: 64 rows x 16 k = 256 float4; thread t: row=t>>2, kq=(t&3)*4
  const int xrow = tid >> 2;
  const int xq   = (tid & 3) * 4;
  const float* xsrc = x + (rowBase + xrow) * (long)IN_DIM + xq;
  // w: 112 rows x 16 k = 448 float4; thread t<224: row=t>>1, skh=(t&1)*8
  const int  wrow = tid >> 1;
  const int  skh  = (tid & 1) * 8;
  const float* wsrc = w1p + (long)wrow * IN_DIM + skh;
  const bool   dow  = tid < 2 * BN;   // 224 threads stage w

  float4 xg, wa, wb;
  auto LOAD = [&](int s) {
    xg = *reinterpret_cast<const float4*>(xsrc + s * KC);
    if (dow) {
      const float4* wp = reinterpret_cast<const float4*>(wsrc + s * KC);
      wa = wp[0]; wb = wp[1];
    }
  };
  auto STORE = [&](int buf) {
    xls[buf][xq + 0][xrow] = xg.x; xls[buf][xq + 1][xrow] = xg.y;
    xls[buf][xq + 2][xrow] = xg.z; xls[buf][xq + 3][xrow] = xg.w;
    if (dow) {
      wls[buf][skh + 0][wrow] = wa.x; wls[buf][skh + 1][wrow] = wa.y;
      wls[buf][skh + 2][wrow] = wa.z; wls[buf][skh + 3][wrow] = wa.w;
      wls[buf][skh + 4][wrow] = wb.x; wls[buf][skh + 5][wrow] = wb.y;
      wls[buf][skh + 6][wrow] = wb.z; wls[buf][skh + 7][wrow] = wb.w;
    }
  };

  // issue first global loads, run calibration probes under their latency
  LOAD(0);

  // ---- self-calibration: discover the true (lane,reg)->(row,col) D map ----
  f64x4 z = {0.0, 0.0, 0.0, 0.0};
  const double eil = (double)il;
  const double d0 = (kg == 0) ? 1.0 : 0.0;
  const double d1 = (kg == 1) ? 1.0 : 0.0;
  const double d2 = (kg == 2) ? 1.0 : 0.0;
  const double d3 = (kg == 3) ? 1.0 : 0.0;
  const f64x4 Prow0 = MFMA64(eil, d0, z);
  const f64x4 Prow1 = MFMA64(eil, d1, z);
  const f64x4 Pcol0 = MFMA64(d0, eil, z);
  const f64x4 Pcol1 = MFMA64(d1, eil, z);
  const f64x4 Pv0   = MFMA64(d0, d0, z);
  const f64x4 Pv1   = MFMA64(d1, d1, z);
  const f64x4 Pv2   = MFMA64(d2, d2, z);
  const f64x4 Pv3   = MFMA64(d3, d3, z);

  bool okl = true;
  int rowof[4], colof[4];
#pragma unroll
  for (int r = 0; r < 4; ++r) {
    okl = okl && (Pv0[r] == 1.0) && (Pv1[r] == 1.0) && (Pv2[r] == 1.0) && (Pv3[r] == 1.0);
    okl = okl && (Prow0[r] == Prow1[r]) && (Pcol0[r] == Pcol1[r]);
    const int rr = (int)Prow0[r];
    const int cc = (int)Pcol0[r];
    okl = okl && ((double)rr == Prow0[r]) && (rr >= 0) && (rr < 16);
    okl = okl && ((double)cc == Pcol0[r]) && (cc >= 0) && (cc < 16);
    rowof[r] = rr; colof[r] = cc;
  }
  if (__all(okl ? 1 : 0) == 0) {       // canonical fallback (not expected)
#pragma unroll
    for (int r = 0; r < 4; ++r) { rowof[r] = kg * 4 + r; colof[r] = il; }
  }

  f64x4 acc[7];
#pragma unroll
  for (int ht = 0; ht < 7; ++ht) acc[ht] = z;

  STORE(0); LOAD(1);
  __syncthreads();

#pragma unroll 1
  for (int s = 0; s < NSTEP; ++s) {
    if (s + 1 < NSTEP) STORE((s + 1) & 1);
    if (s + 2 < NSTEP) LOAD(s + 2);
    const int buf = s & 1;

#pragma unroll
    for (int kk = 0; kk < 4; ++kk) {
      const int kr = kk * 4 + kg;
      const double a0 = (double)xls[buf][kr][wv * 16 + il];
      double b[7];
#pragma unroll
      for (int ht = 0; ht < 7; ++ht)
        b[ht] = (double)wls[buf][kr][ht * 16 + il];
#pragma unroll
      for (int ht = 0; ht < 7; ++ht)
        acc[ht] = MFMA64(a0, b[ht], acc[ht]);
    }
    __syncthreads();
  }

  // epilogue through the calibrated D map
  const long r0 = rowBase + wv * 16;
#pragma unroll
  for (int ht = 0; ht < 7; ++ht)
#pragma unroll
    for (int m = 0; m < 4; ++m)
      cur[(r0 + rowof[m]) * BN + ht * 16 + colof[m]] = acc[ht][m];
}

// ---------------- Phase B: serial-in-time recursion, fp64 state ----------------
// 512 blocks x 4 samples; cur prefetched one step ahead; layer-2 dot split over 2 threads.
__global__ __launch_bounds__(256)
void snn_recur(const double* __restrict__ cur,  // [chunkT][2048][112]
               const float* __restrict__ w2,    // [10][100]
               double* __restrict__ mem1s, float* __restrict__ spk1s,  // [2048][112]
               double* __restrict__ mem2s, float* __restrict__ spk2s,  // [2048][10]
               float* __restrict__ outs,
               float* __restrict__ dout,
               int chunkT, int isFirst, int isLast)
{
  const int tid = threadIdx.x;
  const int b0  = blockIdx.x * 4;              // 4 samples per block
  __shared__ float w2l[OUT_DIM * HID_DIM];     // 1000
  __shared__ float spkl[4 * BN];               // 448

  if (tid < 250)
    reinterpret_cast<float4*>(w2l)[tid] = reinterpret_cast<const float4*>(w2)[tid];

  const bool pa = tid < 112;                   // 4 samples * 112 / 4
  const int  sl = tid / 28, q4 = (tid % 28) * 4;
  const long aOff = (long)(b0 + sl) * BN + q4;
  double m1[4] = {0.0, 0.0, 0.0, 0.0};
  float4 s1 = make_float4(0.f, 0.f, 0.f, 0.f);
  if (pa && !isFirst) {
    const double2* mp = reinterpret_cast<const double2*>(mem1s + aOff);
    double2 a = mp[0], b = mp[1];
    m1[0] = a.x; m1[1] = a.y; m1[2] = b.x; m1[3] = b.y;
    s1 = *reinterpret_cast<const float4*>(spk1s + aOff);
  }

  const bool pb = tid < 80;                    // pair p=tid>>1 -> (sample, out); half=tid&1
  const int  pp = tid >> 1, hf = tid & 1;
  const int  ss = pp / 10, oo = pp % 10;
  const long bOff = (long)b0 * OUT_DIM + pp;
  double m2 = 0.0;
  float s2 = 0.f, oacc = 0.f;
  if (pb && !isFirst && hf == 0) { m2 = mem2s[bOff]; s2 = spk2s[bOff]; oacc = outs[bOff]; }

  __syncthreads();

  // prefetch pipeline on cur
  double2 ca, cb;
  if (pa) {
    const double2* cp = reinterpret_cast<const double2*>(cur + (long)b0 * BN + sl * BN + q4);
    ca = cp[0]; cb = cp[1];
  }

  for (int tt = 0; tt < chunkT; ++tt) {
    if (pa) {
      double cu[4] = {ca.x, ca.y, cb.x, cb.y};
      // issue next-step load now; completes under the dot phase
      const int tn = (tt + 1 < chunkT) ? tt + 1 : tt;
      const double2* cp = reinterpret_cast<const double2*>(
          cur + ((long)tn * B_SZ + b0 + sl) * BN + q4);
      ca = cp[0]; cb = cp[1];

      float4 sp;
      float* spv = &sp.x;
      const float* s1v = &s1.x;
#pragma unroll
      for (int j = 0; j < 4; ++j) {
        double m = 0.9 * m1[j];
        m = m + cu[j];
        m = m - (double)s1v[j];
        spv[j] = (m > 1.0) ? 1.0f : 0.0f;
        m1[j] = m;
      }
      s1 = sp;
      *reinterpret_cast<float4*>(&spkl[sl * BN + q4]) = sp;
    }
    __syncthreads();
    if (pb) {
      const float* sr = &spkl[ss * BN] + hf * 50;
      const float* wr = &w2l[oo * HID_DIM] + hf * 50;
      double a0 = 0.0, a1 = 0.0;
#pragma unroll
      for (int h = 0; h < 50; h += 2) {        // 50 per half; order-free in fp64
        a0 = fma((double)sr[h],     (double)wr[h],     a0);
        a1 = fma((double)sr[h + 1], (double)wr[h + 1], a1);
      }
      double a = a0 + a1;
      a = a + __shfl_xor(a, 1);                // combine halves
      if (hf == 0) {
        double m = 0.9 * m2;
        m = m + a;
        m = m - (double)s2;
        const float sp = (m > 1.0) ? 1.0f : 0.0f;
        m2 = m; s2 = sp; oacc += sp;
      }
    }
    __syncthreads();
  }

  if (pa) {
    double2* mp = reinterpret_cast<double2*>(mem1s + aOff);
    mp[0] = make_double2(m1[0], m1[1]);
    mp[1] = make_double2(m1[2], m1[3]);
    *reinterpret_cast<float4*>(spk1s + aOff) = s1;
  }
  if (pb && hf == 0) {
    mem2s[bOff] = m2; spk2s[bOff] = s2; outs[bOff] = oacc;
    if (isLast) dout[bOff] = oacc;
  }
}

// ---------------- host ----------------
extern "C" void kernel_launch(void* const* d_in, const int* in_sizes, int n_in,
                              void* d_out, int out_size, void* d_ws, size_t ws_size,
                              hipStream_t stream) {
  const float* x  = (const float*)d_in[0];   // [100,2048,784]
  const float* w1 = (const float*)d_in[1];   // [100,784]
  const float* w2 = (const float*)d_in[2];   // [10,100]
  float* out = (float*)d_out;

  char* ws = (char*)d_ws;
  // byte offsets: w1p(f) 351,232 | mem1(d) 1,835,008 | spk1(f) 917,504 |
  //               mem2(d) 163,840 | spk2(f) 81,920 | outacc(f) 81,920 | cur(d)...
  float*  w1p   = (float*) (ws);
  double* mem1s = (double*)(ws +  351232);
  float*  spk1s = (float*) (ws + 2186240);
  double* mem2s = (double*)(ws + 3103744);
  float*  spk2s = (float*) (ws + 3267584);
  float*  outs  = (float*) (ws + 3349504);
  double* cur   = (double*)(ws + 3431424);

  pad_w1<<<dim3((BN * IN_DIM + 255) / 256), dim3(256), 0, stream>>>(w1, w1p);

  const size_t perT = (size_t)B_SZ * BN * 8;   // 1,835,008 B of cur per timestep
  size_t curCap = ws_size > (size_t)3431424 ? ws_size - 3431424 : 0;
  int Tc = (int)(curCap / perT);
  if (Tc > T_STEPS) Tc = T_STEPS;
  if (Tc < 1) Tc = 1;

  for (int t0 = 0; t0 < T_STEPS; t0 += Tc) {
    const int ct = (T_STEPS - t0 < Tc) ? (T_STEPS - t0) : Tc;
    snn_gemm1<<<dim3(ct * (B_SZ / BMR)), dim3(256), 0, stream>>>(
        x + (size_t)t0 * B_SZ * IN_DIM, w1p, cur);
    snn_recur<<<dim3(B_SZ / 4), dim3(256), 0, stream>>>(
        cur, w2, mem1s, spk1s, mem2s, spk2s, outs, out,
        ct, (t0 == 0) ? 1 : 0, (t0 + ct >= T_STEPS) ? 1 : 0);
  }
}